// Round 14
// baseline (945.211 us; speedup 1.0000x reference)
//
#include <hip/hip_runtime.h>
#include <stdint.h>

#define N_ROWS 8192
#define DDIM   512

typedef __bf16 bf16_t;
typedef bf16_t bf16x8 __attribute__((ext_vector_type(8)));
typedef float  f32x4  __attribute__((ext_vector_type(4)));

#define MFMA16 __builtin_amdgcn_mfma_f32_16x16x32_bf16

// ---------------- f32 -> bf16 (RNE) convert, vectorized ----------------
__device__ inline uint16_t f2bf(float f) {
    uint32_t u = __float_as_uint(f);
    u += 0x7FFFu + ((u >> 16) & 1u);
    return (uint16_t)(u >> 16);
}

__global__ void convert_bf16(const float* __restrict__ a, const float* __restrict__ b,
                             uint16_t* __restrict__ abf, uint16_t* __restrict__ bbf) {
    const int quads = N_ROWS * DDIM / 4;
    const int stride = gridDim.x * blockDim.x;
    for (int i = blockIdx.x * blockDim.x + threadIdx.x; i < quads; i += stride) {
        float4 va = ((const float4*)a)[i];
        float4 vb = ((const float4*)b)[i];
        ushort4 ra, rb;
        ra.x = f2bf(va.x); ra.y = f2bf(va.y); ra.z = f2bf(va.z); ra.w = f2bf(va.w);
        rb.x = f2bf(vb.x); rb.y = f2bf(vb.y); rb.z = f2bf(vb.z); rb.w = f2bf(vb.w);
        ((ushort4*)abf)[i] = ra;
        ((ushort4*)bbf)[i] = rb;
    }
}

// ---------------- async global->LDS 16B stage ----------------
__device__ inline void stage16(const uint8_t* g, uint8_t* lds_wave_base) {
#if __has_builtin(__builtin_amdgcn_global_load_lds)
    __builtin_amdgcn_global_load_lds(
        (const __attribute__((address_space(1))) uint32_t*)g,
        (__attribute__((address_space(3))) uint32_t*)lds_wave_base, 16, 0, 0);
#else
    *(int4*)(lds_wave_base) = *(const int4*)g;
#endif
}

// ============================================================================
// R14: TWO BLOCKS PER CU. R9 proved the three subsystems serialize within a
// block under every schedule (R5-R10 all ~30% MfmaUtil, 1 block/CU at 128 KB
// LDS). m97/m114 evidence: cross-BLOCK wave overlap is the mechanism that
// hides the serial phases (m97's 874 TF ran ~3 blocks/CU). So: single 64 KB
// LDS buffer (A 32K + B 32K) -> 2 blocks/CU, 16 waves. m97-style loop:
//   STAGE8(tt) -> barrier (compiler auto-drains vmcnt) -> LOAD12+MMA x2
//   -> barrier (WAR).
// Block A's stage/drain hides under block B's MFMA and vice versa.
// All proven pieces kept byte-exact: 128B rows, granule slot g^(r&7), read
// slot (kk*4+lg)^l7 (0 conflicts, R5/R7/R9/R10), inverse-swizzled staging
// source + linear LDS dest (rule #21), 2D-chunked XCD swizzle (FETCH 24.7MB),
// verified 16x16 epilogue.
// ============================================================================
__global__ void __launch_bounds__(512, 4)
clip_gemm(const uint16_t* __restrict__ A, const uint16_t* __restrict__ B,
          const float* __restrict__ scale_p,
          float* __restrict__ rowsum, float* __restrict__ colsum,
          float* __restrict__ diag) {
    __shared__ __attribute__((aligned(16))) uint8_t sh[65536];   // A[0,32K) B[32K,64K)

    const int t    = threadIdx.x;
    const int wave = t >> 6;
    const int lane = t & 63;
    const int wm   = wave >> 2;    // 0..1  (M half: 128 rows)
    const int wn   = wave & 3;     // 0..3  (N slice: 64 cols)
    const int lr   = lane & 15;
    const int lg   = lane >> 4;
    const int l7   = lane & 7;

    // 2D-chunked XCD swizzle (proven): xcd owns 8bm x 16bn, bm-fastest.
    const int orig = blockIdx.x;               // 0..1023
    const int xcd  = orig & 7;
    const int idx  = orig >> 3;                // 0..127
    const int bm   = (xcd & 3) * 8  + (idx & 7);
    const int bn   = (xcd >> 2) * 16 + (idx >> 3);

    const float s     = *scale_p;
    const float shift = s - 64.0f;

    f32x4 acc[8][4];
#pragma unroll
    for (int i = 0; i < 8; ++i)
#pragma unroll
        for (int j = 0; j < 4; ++j)
#pragma unroll
            for (int r = 0; r < 4; ++r) acc[i][j][r] = 0.0f;

    // staging source (inverse-swizzled): thread t supplies row c*64+(t>>3),
    // granule (t&7)^((t>>3)&7) of K-tile kt. LDS dest linear.
    const int g16 = (((t & 7) ^ ((t >> 3) & 7)) << 4);
    const uint8_t* srcA = (const uint8_t*)A + (size_t)(bm * 256 + (t >> 3)) * 1024 + g16;
    const uint8_t* srcB = (const uint8_t*)B + (size_t)(bn * 256 + (t >> 3)) * 1024 + g16;
    uint8_t* dA = sh + wave * 1024;
    uint8_t* dB = sh + 32768 + wave * 1024;

#define STAGE8(kt) do {                                                         \
        _Pragma("unroll")                                                       \
        for (int c = 0; c < 4; ++c) {                                           \
            stage16(srcA + (size_t)(kt) * 128 + (size_t)c * 65536,              \
                    dA + c * 8192);                                             \
            stage16(srcB + (size_t)(kt) * 128 + (size_t)c * 65536,              \
                    dB + c * 8192);                                             \
        }                                                                       \
    } while (0)

    // fragment read offsets: chunk octet (kk*4+lg) ^ (lane&7)  [0 conflicts,
    // measured R5/R7/R9/R10 — byte-exact golden pattern, 128B rows]
    const int x0   = ((lg) ^ l7) << 4;        // kk=0
    const int x1   = ((4 | lg) ^ l7) << 4;    // kk=1
    const int aRow = (wm * 128 + lr) * 128;
    const int bRow = 32768 + (wn * 64 + lr) * 128;

    bf16x8 aC[8], bC[4], aN[8], bN[4];

#define LOAD12(AF, BF, X) do {                                                  \
        _Pragma("unroll")                                                       \
        for (int i = 0; i < 8; ++i)                                             \
            AF[i] = *(const bf16x8*)(sh + aRow + i * 2048 + (X));               \
        _Pragma("unroll")                                                       \
        for (int j = 0; j < 4; ++j)                                             \
            BF[j] = *(const bf16x8*)(sh + bRow + j * 2048 + (X));               \
    } while (0)

#define MMA32(AF, BF) do {                                                      \
        __builtin_amdgcn_s_setprio(1);                                          \
        _Pragma("unroll")                                                       \
        for (int i = 0; i < 8; ++i)                                             \
            _Pragma("unroll")                                                   \
            for (int j = 0; j < 4; ++j)                                         \
                acc[i][j] = MFMA16(AF[i], BF[j], acc[i][j], 0, 0, 0);           \
        __builtin_amdgcn_s_setprio(0);                                          \
    } while (0)

    // ---------------- main loop: 8 K-tiles, single buffer ----------------
    for (int tt = 0; tt < 8; ++tt) {
        STAGE8(tt);
        __syncthreads();          // compiler auto-drains vmcnt(0): tile resident
        LOAD12(aC, bC, x0);       // kk=0
        LOAD12(aN, bN, x1);       // kk=1 (issued before MMA; compiler interleaves)
        MMA32(aC, bC);
        MMA32(aN, bN);
        __syncthreads();          // WAR: everyone done reading before overwrite
    }
#undef STAGE8
#undef LOAD12
#undef MMA32

    // ---------------- epilogue: exp + reductions ----------------
    // D layout (16x16): col = lr, row = lg*4 + r  (verified R1/R5/R7).
    float cp[4] = {0.f, 0.f, 0.f, 0.f};
#pragma unroll
    for (int i = 0; i < 8; ++i) {
        float rp[4] = {0.f, 0.f, 0.f, 0.f};
#pragma unroll
        for (int j = 0; j < 4; ++j) {
#pragma unroll
            for (int r = 0; r < 4; ++r) {
                const float logit = s * acc[i][j][r];
                const float e = __expf(logit - shift);
                rp[r] += e;
                cp[j] += e;
                if (bm == bn) {
                    const int rr = wm * 128 + i * 16 + lg * 4 + r;
                    const int cc = wn * 64 + j * 16 + lr;
                    if (rr == cc) diag[bm * 256 + rr] = logit;
                }
            }
        }
#pragma unroll
        for (int r = 0; r < 4; ++r) {
            float v = rp[r];
            v += __shfl_xor(v, 1);
            v += __shfl_xor(v, 2);
            v += __shfl_xor(v, 4);
            v += __shfl_xor(v, 8);
            if (lr == 0)
                atomicAdd(&rowsum[bm * 256 + wm * 128 + i * 16 + lg * 4 + r], v);
        }
    }
#pragma unroll
    for (int j = 0; j < 4; ++j) {
        float v = cp[j];
        v += __shfl_xor(v, 16);
        v += __shfl_xor(v, 32);
        if (lg == 0)
            atomicAdd(&colsum[bn * 256 + wn * 64 + j * 16 + lr], v);
    }
}

// ---------------- final reduce: loss scalar (parallel) ----------------
__global__ void clip_finalize(const float* __restrict__ rowsum, const float* __restrict__ colsum,
                              const float* __restrict__ diag, const float* __restrict__ scale_p,
                              float* __restrict__ out) {
    __shared__ float red[4];
    const float s = *scale_p;
    const float shift = s - 64.0f;
    const int i = blockIdx.x * 256 + threadIdx.x;   // grid 32 x 256 = 8192
    float acc = logf(rowsum[i]) + logf(colsum[i]) + 2.f * shift - 2.f * diag[i];
#pragma unroll
    for (int m = 1; m < 64; m <<= 1) acc += __shfl_xor(acc, m);
    const int wave = threadIdx.x >> 6;
    const int lane = threadIdx.x & 63;
    if (lane == 0) red[wave] = acc;
    __syncthreads();
    if (threadIdx.x == 0) {
        atomicAdd(out, (red[0] + red[1] + red[2] + red[3]) / (2.0f * N_ROWS));
    }
}

extern "C" void kernel_launch(void* const* d_in, const int* in_sizes, int n_in,
                              void* d_out, int out_size, void* d_ws, size_t ws_size,
                              hipStream_t stream) {
    const float* img     = (const float*)d_in[0];
    const float* txt     = (const float*)d_in[1];
    const float* scale_p = (const float*)d_in[2];

    uint8_t* ws = (uint8_t*)d_ws;
    uint16_t* Abf   = (uint16_t*)ws;                                  // 8 MB
    uint16_t* Bbf   = (uint16_t*)(ws + (size_t)8 * 1024 * 1024);      // 8 MB
    float*    rowsum = (float*)(ws + (size_t)16 * 1024 * 1024);       // 32 KB
    float*    colsum = rowsum + N_ROWS;                               // 32 KB
    float*    diag   = colsum + N_ROWS;                               // 32 KB
    float*    out    = (float*)d_out;

    hipMemsetAsync(rowsum, 0, 2 * N_ROWS * sizeof(float), stream);
    hipMemsetAsync(out, 0, sizeof(float), stream);
    convert_bf16<<<1024, 256, 0, stream>>>(img, txt, Abf, Bbf);
    clip_gemm<<<1024, 512, 0, stream>>>(Abf, Bbf, scale_p, rowsum, colsum, diag);
    clip_finalize<<<32, 256, 0, stream>>>(rowsum, colsum, diag, scale_p, out);
}

// Round 15
// 120.148 us; speedup vs baseline: 7.8671x; 7.8671x over previous
//
#include <hip/hip_runtime.h>
#include <stdint.h>

#define N_ROWS 8192
#define DDIM   512

typedef __bf16 bf16_t;
typedef bf16_t bf16x8 __attribute__((ext_vector_type(8)));
typedef float  f32x4  __attribute__((ext_vector_type(4)));

#define MFMA16 __builtin_amdgcn_mfma_f32_16x16x32_bf16

// ---------------- f32 -> bf16 (RNE) convert, vectorized ----------------
__device__ inline uint16_t f2bf(float f) {
    uint32_t u = __float_as_uint(f);
    u += 0x7FFFu + ((u >> 16) & 1u);
    return (uint16_t)(u >> 16);
}

__global__ void convert_bf16(const float* __restrict__ a, const float* __restrict__ b,
                             uint16_t* __restrict__ abf, uint16_t* __restrict__ bbf) {
    const int quads = N_ROWS * DDIM / 4;
    const int stride = gridDim.x * blockDim.x;
    for (int i = blockIdx.x * blockDim.x + threadIdx.x; i < quads; i += stride) {
        float4 va = ((const float4*)a)[i];
        float4 vb = ((const float4*)b)[i];
        ushort4 ra, rb;
        ra.x = f2bf(va.x); ra.y = f2bf(va.y); ra.z = f2bf(va.z); ra.w = f2bf(va.w);
        rb.x = f2bf(vb.x); rb.y = f2bf(vb.y); rb.z = f2bf(vb.z); rb.w = f2bf(vb.w);
        ((ushort4*)abf)[i] = ra;
        ((ushort4*)bbf)[i] = rb;
    }
}

// ---------------- async global->LDS 16B stage ----------------
__device__ inline void stage16(const uint8_t* g, uint8_t* lds_wave_base) {
#if __has_builtin(__builtin_amdgcn_global_load_lds)
    __builtin_amdgcn_global_load_lds(
        (const __attribute__((address_space(1))) uint32_t*)g,
        (__attribute__((address_space(3))) uint32_t*)lds_wave_base, 16, 0, 0);
#else
    *(int4*)(lds_wave_base) = *(const int4*)g;
#endif
}

// ============================================================================
// R15: m97-class config — the one that FITS multi-block residency.
// R14 lesson: 256²/8-wave needs ~190 regs/wave -> can never co-reside 2 blocks
// (512-reg/SIMD pool). R9 proved within-block phases serialize; the m97/m114
// overlap mechanism is CROSS-BLOCK. So: 128² tile, 256 thr / 4 waves (2Mx2N),
// acc[4][4]=64 regs -> ~100 VGPR -> 3-4 blocks/CU.
// BK=64 => 128B LDS rows => golden conflict-free read slot (kk*4+lg)^l7
// (0 conflicts measured R5/R7/R9/R10/R12; 64B rows measured 8.4M in R1/R13).
// Single 32 KB buffer, m97 2-barrier loop, 8 K-tiles. Staging source
// inverse-swizzled, LDS dest linear (rule #21). 2D XCD chunk: xcd owns
// 16bm x 32bn, bm-fastest (R5-proven family). Epilogue = R1-verified.
// ============================================================================
__global__ void __launch_bounds__(256)
clip_gemm(const uint16_t* __restrict__ A, const uint16_t* __restrict__ B,
          const float* __restrict__ scale_p,
          float* __restrict__ rowsum, float* __restrict__ colsum,
          float* __restrict__ diag) {
    __shared__ __attribute__((aligned(16))) uint8_t sh[32768];  // A[0,16K) B[16K,32K)

    const int t    = threadIdx.x;
    const int wave = t >> 6;
    const int lane = t & 63;
    const int wr   = wave >> 1;   // 0..1 : wave row (64 rows)
    const int wc   = wave & 1;    // 0..1 : wave col (64 cols)
    const int lr   = lane & 15;
    const int lg   = lane >> 4;
    const int l7   = lane & 7;

    // 2D XCD chunk: xcd owns 16bm x 32bn, bm-fastest (concurrent ~12-16
    // blocks share one bn => A-band 2MB + B-tile L2-resident).
    const int orig = blockIdx.x;               // 0..4095
    const int xcd  = orig & 7;
    const int idx  = orig >> 3;                // 0..511
    const int bm   = (xcd >> 1) * 16 + (idx & 15);   // 0..63
    const int bn   = (xcd & 1) * 32 + (idx >> 4);    // 0..63

    const float s     = *scale_p;
    const float shift = s - 64.0f;

    f32x4 acc[4][4];
#pragma unroll
    for (int m = 0; m < 4; ++m)
#pragma unroll
        for (int n = 0; n < 4; ++n)
#pragma unroll
            for (int r = 0; r < 4; ++r) acc[m][n][r] = 0.0f;

    // staging source (inverse-swizzled): thread t supplies row c*32+(t>>3),
    // granule (t&7)^((t>>3)&7) of the 128B k-window. LDS dest linear.
    const int g16 = (((t & 7) ^ ((t >> 3) & 7)) << 4);
    const uint8_t* srcA = (const uint8_t*)A + (size_t)(bm * 128 + (t >> 3)) * 1024 + g16;
    const uint8_t* srcB = (const uint8_t*)B + (size_t)(bn * 128 + (t >> 3)) * 1024 + g16;
    uint8_t* dA = sh + wave * 1024;            // + c*4096
    uint8_t* dB = sh + 16384 + wave * 1024;

#define STAGE(kt) do {                                                          \
        _Pragma("unroll")                                                       \
        for (int c = 0; c < 4; ++c) {                                           \
            stage16(srcA + (size_t)(kt) * 128 + (size_t)c * 32768,              \
                    dA + c * 4096);                                             \
            stage16(srcB + (size_t)(kt) * 128 + (size_t)c * 32768,              \
                    dB + c * 4096);                                             \
        }                                                                       \
    } while (0)

    // golden read offsets (128B rows): chunk (kk*4+lg) ^ l7
    const int x0   = ((lg) ^ l7) << 4;        // kk=0
    const int x1   = ((4 | lg) ^ l7) << 4;    // kk=1
    const int aRow = (wr * 64 + lr) * 128;
    const int bRow = 16384 + (wc * 64 + lr) * 128;

    bf16x8 a[4], b[4];

#define LOAD8(X) do {                                                           \
        _Pragma("unroll")                                                       \
        for (int m = 0; m < 4; ++m)                                             \
            a[m] = *(const bf16x8*)(sh + aRow + m * 2048 + (X));                \
        _Pragma("unroll")                                                       \
        for (int n = 0; n < 4; ++n)                                             \
            b[n] = *(const bf16x8*)(sh + bRow + n * 2048 + (X));                \
    } while (0)

#define MMA16() do {                                                            \
        __builtin_amdgcn_s_setprio(1);                                          \
        _Pragma("unroll")                                                       \
        for (int m = 0; m < 4; ++m)                                             \
            _Pragma("unroll")                                                   \
            for (int n = 0; n < 4; ++n)                                         \
                acc[m][n] = MFMA16(a[m], b[n], acc[m][n], 0, 0, 0);             \
        __builtin_amdgcn_s_setprio(0);                                          \
    } while (0)

    // ---------------- main loop: 8 K-tiles of 64, single buffer ----------------
    for (int tt = 0; tt < 8; ++tt) {
        STAGE(tt);
        __syncthreads();          // auto-drains vmcnt: tile resident
        LOAD8(x0);
        MMA16();                  // kk=0
        LOAD8(x1);
        MMA16();                  // kk=1
        __syncthreads();          // WAR before overwrite
    }
#undef STAGE
#undef LOAD8
#undef MMA16

    // ---------------- epilogue: exp + reductions (R1-verified) ----------------
    // D layout: col = lr, row = lg*4 + r
    float rpart[4][4];
    float cpart[4] = {0.f, 0.f, 0.f, 0.f};
#pragma unroll
    for (int m = 0; m < 4; ++m)
#pragma unroll
        for (int r = 0; r < 4; ++r) rpart[m][r] = 0.f;

#pragma unroll
    for (int m = 0; m < 4; ++m) {
#pragma unroll
        for (int n = 0; n < 4; ++n) {
#pragma unroll
            for (int r = 0; r < 4; ++r) {
                const float logit = s * acc[m][n][r];
                const float e = __expf(logit - shift);
                rpart[m][r] += e;
                cpart[n]    += e;
                if (bm == bn && wr == wc && m == n && lr == lg * 4 + r)
                    diag[bm * 128 + wr * 64 + m * 16 + lr] = logit;
            }
        }
    }

#pragma unroll
    for (int m = 0; m < 4; ++m) {
#pragma unroll
        for (int r = 0; r < 4; ++r) {
            float v = rpart[m][r];
            v += __shfl_xor(v, 1);
            v += __shfl_xor(v, 2);
            v += __shfl_xor(v, 4);
            v += __shfl_xor(v, 8);
            if (lr == 0)
                atomicAdd(&rowsum[bm * 128 + wr * 64 + m * 16 + lg * 4 + r], v);
        }
    }
#pragma unroll
    for (int n = 0; n < 4; ++n) {
        float v = cpart[n];
        v += __shfl_xor(v, 16);
        v += __shfl_xor(v, 32);
        if (lg == 0)
            atomicAdd(&colsum[bn * 128 + wc * 64 + n * 16 + lr], v);
    }
}

// ---------------- final reduce: loss scalar (parallel) ----------------
__global__ void clip_finalize(const float* __restrict__ rowsum, const float* __restrict__ colsum,
                              const float* __restrict__ diag, const float* __restrict__ scale_p,
                              float* __restrict__ out) {
    __shared__ float red[4];
    const float s = *scale_p;
    const float shift = s - 64.0f;
    const int i = blockIdx.x * 256 + threadIdx.x;   // grid 32 x 256 = 8192
    float acc = logf(rowsum[i]) + logf(colsum[i]) + 2.f * shift - 2.f * diag[i];
#pragma unroll
    for (int m = 1; m < 64; m <<= 1) acc += __shfl_xor(acc, m);
    const int wave = threadIdx.x >> 6;
    const int lane = threadIdx.x & 63;
    if (lane == 0) red[wave] = acc;
    __syncthreads();
    if (threadIdx.x == 0) {
        atomicAdd(out, (red[0] + red[1] + red[2] + red[3]) / (2.0f * N_ROWS));
    }
}

extern "C" void kernel_launch(void* const* d_in, const int* in_sizes, int n_in,
                              void* d_out, int out_size, void* d_ws, size_t ws_size,
                              hipStream_t stream) {
    const float* img     = (const float*)d_in[0];
    const float* txt     = (const float*)d_in[1];
    const float* scale_p = (const float*)d_in[2];

    uint8_t* ws = (uint8_t*)d_ws;
    uint16_t* Abf   = (uint16_t*)ws;                                  // 8 MB
    uint16_t* Bbf   = (uint16_t*)(ws + (size_t)8 * 1024 * 1024);      // 8 MB
    float*    rowsum = (float*)(ws + (size_t)16 * 1024 * 1024);       // 32 KB
    float*    colsum = rowsum + N_ROWS;                               // 32 KB
    float*    diag   = colsum + N_ROWS;                               // 32 KB
    float*    out    = (float*)d_out;

    hipMemsetAsync(rowsum, 0, 2 * N_ROWS * sizeof(float), stream);
    hipMemsetAsync(out, 0, sizeof(float), stream);
    convert_bf16<<<1024, 256, 0, stream>>>(img, txt, Abf, Bbf);
    clip_gemm<<<4096, 256, 0, stream>>>(Abf, Bbf, scale_p, rowsum, colsum, diag);
    clip_finalize<<<32, 256, 0, stream>>>(rowsum, colsum, diag, scale_p, out);
}